// Round 14
// baseline (346.352 us; speedup 1.0000x reference)
//
#include <hip/hip_runtime.h>
#include <hip/hip_bf16.h>

typedef __bf16 bf16_t;
typedef __bf16 bf16x4 __attribute__((ext_vector_type(4)));
typedef __bf16 bf16x8 __attribute__((ext_vector_type(8)));
typedef float f32x2 __attribute__((ext_vector_type(2)));
typedef float f32x4 __attribute__((ext_vector_type(4)));

__device__ __forceinline__ void gload16(const void* g, void* l) {
  __builtin_amdgcn_global_load_lds((const __attribute__((address_space(1))) void*)g,
                                   (__attribute__((address_space(3))) void*)l, 16, 0, 0);
}

#define VMW(n) asm volatile("s_waitcnt vmcnt(" #n ")" ::: "memory")

// ---------------- prep: fold proj into w_qkv (q,k halves) ----------------
__global__ __launch_bounds__(256) void prep_qk(const float* __restrict__ w_qkv,
                                               const float* __restrict__ proj,
                                               bf16_t* __restrict__ WeffT) {
  const int half = blockIdx.x >> 3, h = blockIdx.x & 7;
  const int i0 = blockIdx.y * 64;
  __shared__ float P[64 * 64];   // [d][f] == proj[h] layout
  __shared__ float Wt[64][65];   // [ii][d], padded
  const int t = threadIdx.x;
  #pragma unroll
  for (int r = 0; r < 16; ++r) P[t + 256 * r] = proj[(size_t)h * 4096 + t + 256 * r];
  #pragma unroll
  for (int r = 0; r < 16; ++r) {
    const int idx = t + 256 * r;
    Wt[idx >> 6][idx & 63] =
        w_qkv[(size_t)(i0 + (idx >> 6)) * 1536 + half * 512 + h * 64 + (idx & 63)];
  }
  __syncthreads();
  const int i = t & 63, fg = t >> 6;
  for (int f = fg; f < 64; f += 4) {
    float s = 0.f;
    #pragma unroll
    for (int d = 0; d < 64; ++d) s += Wt[i][d] * P[d * 64 + f];
    WeffT[(size_t)(half * 512 + h * 64 + f) * 512 + i0 + i] = (bf16_t)s;
  }
}

// ---------------- prep: v passthrough transpose ----------------
__global__ __launch_bounds__(256) void prep_v(const float* __restrict__ w_qkv,
                                              bf16_t* __restrict__ WeffT) {
  __shared__ bf16_t tile[32][33];
  const int i0 = blockIdx.x * 32, n0 = blockIdx.y * 32;
  const int tn = threadIdx.x & 31, ti = threadIdx.x >> 5;
  #pragma unroll
  for (int p = 0; p < 4; ++p) {
    const int i = ti + p * 8;
    tile[i][tn] = (bf16_t)w_qkv[(size_t)(i0 + i) * 1536 + 1024 + n0 + tn];
  }
  __syncthreads();
  #pragma unroll
  for (int p = 0; p < 4; ++p) {
    const int n = ti + p * 8;
    WeffT[(size_t)(1024 + n0 + n) * 512 + i0 + tn] = tile[tn][n];
  }
}

// ==================== merged QKV GEMM v7: fused cast, x direct-from-global ====================
// R11 skeleton (3072 blocks x 256 thr, XCD-chunked, fenced __syncthreads/K-step, BK=32,
// 16 K-steps) with the F LDS tile DELETED: x fragments are loaded straight from global
// (two f32x4 = 32B contiguous per fragment row), one full K-step ahead into a register
// double-buffer (static indices via full unroll), cvt f32->bf16 in-register at use.
// LDS: H (WeffT bf16 [128][32], 8KB) x2 bufs in [0,16K); epilogue reuses [0,32K).
// H swizzle: unit u of row r holds global col (u ^ ((r>>1)&3)) — R11's verified pattern.
// x has no cross-wave reuse within a block (each element read once) — L2 serves the
// 12x cross-block reuse; wave covers 128B contiguous per row so line locality holds.
__global__ __launch_bounds__(256) void gemm_qkv(const float* __restrict__ x,
                                                const bf16_t* __restrict__ WeffT,
                                                bf16_t* __restrict__ q_phi,
                                                bf16_t* __restrict__ kT,
                                                bf16_t* __restrict__ vT) {
  __shared__ alignas(16) char smem[32768];  // H bufs [0,8K),[8K,16K); epilogue [0,32K)
  const int t = threadIdx.x, w = t >> 6, l = t & 63;
  const int wr = w >> 1, wc = w & 1;
  const int lrow = l & 15, lkb = l >> 4;
  const int hw = blockIdx.x;
  const int bid = (hw & 7) * 384 + (hw >> 3);   // XCD-chunked (3072/8=384)
  const int tok_blk = bid / 12, cb = bid % 12;
  const size_t tok0 = (size_t)tok_blk * 128;
  const bool qpath = (cb < 4);
  const float* Xp = x + tok0 * 512;
  const bf16_t* Wp = WeffT + (size_t)(qpath ? cb * 128 : 512 + (cb - 4) * 128) * 512;

  // H staging: [128 rows][32 k] bf16, 64B/row, 4x16B units; pre-swizzled source.
  const int h_row = t >> 2;                       // 0..63 (+c*64)
  const int h_u = (t & 3) ^ ((t >> 3) & 3);       // src unit = u ^ ((h_row>>1)&3)
  auto stageH = [&](int s) {
    char* dst = smem + (s & 1) * 8192;
    #pragma unroll
    for (int c = 0; c < 2; ++c)
      gload16(Wp + (size_t)(c * 64 + h_row) * 512 + s * 32 + h_u * 8, dst + c * 4096 + t * 16);
  };

  // x fragment rows: q-path uses wc (Q operand), kv-path uses wr (P operand)
  const int xrbase = (qpath ? wc : wr) * 64 + lrow;
  f32x4 xr32[2][4][2];  // [set][fragment][2x f32x4] — static indices after full unroll
  auto loadX = [&](int s) {
    #pragma unroll
    for (int i = 0; i < 4; ++i) {
      const float* p = Xp + (size_t)(xrbase + i * 16) * 512 + s * 32 + lkb * 8;
      xr32[s & 1][i][0] = *(const f32x4*)p;
      xr32[s & 1][i][1] = *(const f32x4*)(p + 4);
    }
  };

  f32x4 acc[4][4];
  #pragma unroll
  for (int m = 0; m < 4; ++m)
    #pragma unroll
    for (int n = 0; n < 4; ++n) acc[m][n] = f32x4{0.f, 0.f, 0.f, 0.f};

  stageH(0);
  loadX(0);
  __syncthreads();  // drains H(0) and X(0)

  #pragma unroll
  for (int kt = 0; kt < 16; ++kt) {
    if (kt + 1 < 16) { stageH(kt + 1); loadX(kt + 1); }  // one iter ahead
    const char* Hs = smem + (kt & 1) * 8192;
    bf16x8 hf[4], xf[4];
    #pragma unroll
    for (int i = 0; i < 4; ++i) {
      const int r = (qpath ? wr : wc) * 64 + i * 16 + lrow;   // WeffT fragment rows
      hf[i] = *(const bf16x8*)(Hs + r * 64 + ((lkb ^ ((r >> 1) & 3)) << 4));
    }
    #pragma unroll
    for (int i = 0; i < 4; ++i) {
      #pragma unroll
      for (int j = 0; j < 4; ++j) {
        xf[i][j]     = (bf16_t)xr32[kt & 1][i][0][j];
        xf[i][4 + j] = (bf16_t)xr32[kt & 1][i][1][j];
      }
    }
    if (qpath) {
      #pragma unroll
      for (int m = 0; m < 4; ++m)
        #pragma unroll
        for (int n = 0; n < 4; ++n)
          acc[m][n] = __builtin_amdgcn_mfma_f32_16x16x32_bf16(hf[m], xf[n], acc[m][n], 0, 0, 0);
    } else {
      #pragma unroll
      for (int m = 0; m < 4; ++m)
        #pragma unroll
        for (int n = 0; n < 4; ++n)
          acc[m][n] = __builtin_amdgcn_mfma_f32_16x16x32_bf16(xf[m], hf[n], acc[m][n], 0, 0, 0);
    }
    __syncthreads();  // readers done with H buf; H(kt+1)/X(kt+1) landed
  }

  // ---- epilogue: restage tile [128 qrows][128 prows] bf16 in LDS, coalesced store ----
  bf16_t* ep = (bf16_t*)smem;  // 32 KB, rows 256 B, 16-B-unit XOR swizzle (R10/R11 layout)
  const bool doElu = qpath || (cb < 8);  // q and k get elu+1; v passthrough
  #pragma unroll
  for (int n = 0; n < 4; ++n) {
    const int qc = wc * 64 + n * 16 + lrow;
    #pragma unroll
    for (int m = 0; m < 4; ++m) {
      const int pr0 = wr * 64 + m * 16 + lkb * 4;
      bf16x4 o;
      #pragma unroll
      for (int j = 0; j < 4; ++j) {
        float v = acc[m][n][j];
        if (doElu) v = v > 0.f ? v + 1.f : __expf(v);
        o[j] = (bf16_t)v;
      }
      const int u = pr0 >> 3;
      *(bf16x4*)((char*)ep + qc * 256 + ((u ^ (qc & 15)) << 4) + (pr0 & 7) * 2) = o;
    }
  }
  __syncthreads();
  #pragma unroll
  for (int i = 0; i < 8; ++i) {
    const int flat = i * 256 + t;
    const int qc2 = flat >> 4, u2 = flat & 15;
    bf16x8 vv = *(const bf16x8*)((char*)ep + qc2 * 256 + ((u2 ^ (qc2 & 15)) << 4));
    if (qpath) {
      *(bf16x8*)&q_phi[(tok0 + qc2) * 512 + cb * 128 + u2 * 8] = vv;
    } else {
      const int f512 = (cb - 4) * 128 + qc2;  // 0..1023: k then v
      bf16_t* dst = (f512 < 512 ? kT + ((size_t)(tok0 >> 12) * 512 + f512) * 4096
                                : vT + ((size_t)(tok0 >> 12) * 512 + (f512 - 512)) * 4096) +
                    (tok0 & 4095) + u2 * 8;
      *(bf16x8*)dst = vv;
    }
  }
}

// ---------------- kv[f][d] = sum_n kT[f][n]*vT[d][n]; ksum[f] = sum_n kT[f][n] ----
__global__ __launch_bounds__(256) void kv_mfma(const bf16_t* __restrict__ kT,
                                               const bf16_t* __restrict__ vT,
                                               float* __restrict__ kv,
                                               float* __restrict__ ksum) {
  const int bh = blockIdx.x;
  const int nbase = blockIdx.y * 512;
  __shared__ alignas(16) char smem[32768];  // 2 bufs x (K 8K + V 8K)
  const int t = threadIdx.x, w = t >> 6, l = t & 63;
  const int wr = w >> 1, wc = w & 1;
  const int lrow = l & 15, lkb = l >> 4;
  const int st_r = l >> 3;
  const int st_c = ((l & 7) ^ st_r) * 8;
  const bf16_t* Kp = kT + (size_t)bh * 64 * 4096;
  const bf16_t* Vp = vT + (size_t)bh * 64 * 4096;

  f32x4 acc[2][2];
  #pragma unroll
  for (int m = 0; m < 2; ++m)
    #pragma unroll
    for (int n = 0; n < 2; ++n) acc[m][n] = f32x4{0.f, 0.f, 0.f, 0.f};
  float ksf[2] = {0.f, 0.f};

  #pragma unroll
  for (int c = 0; c < 2; ++c) {
    const int q8 = w * 2 + c;
    gload16(Kp + (size_t)(q8 * 8 + st_r) * 4096 + nbase + st_c, smem + q8 * 1024);
    gload16(Vp + (size_t)(q8 * 8 + st_r) * 4096 + nbase + st_c, smem + 8192 + q8 * 1024);
  }
  __syncthreads();

  int cur = 0;
  for (int st = 0; st < 8; ++st) {
    if (st < 7) {
      char* nb = smem + (cur ^ 1) * 16384;
      const int nb2 = nbase + (st + 1) * 64;
      #pragma unroll
      for (int c = 0; c < 2; ++c) {
        const int q8 = w * 2 + c;
        gload16(Kp + (size_t)(q8 * 8 + st_r) * 4096 + nb2 + st_c, nb + q8 * 1024);
        gload16(Vp + (size_t)(q8 * 8 + st_r) * 4096 + nb2 + st_c, nb + 8192 + q8 * 1024);
      }
    }
    const char* KsB = smem + cur * 16384;
    const char* VsB = KsB + 8192;
    bf16x8 af[2][2], bf[2][2];
    #pragma unroll
    for (int m = 0; m < 2; ++m) {
      const int r = wr * 32 + m * 16 + lrow;
      #pragma unroll
      for (int kk = 0; kk < 2; ++kk) {
        const int kb = lkb + kk * 4;
        af[m][kk] = *(const bf16x8*)(KsB + r * 128 + (((kb ^ (r & 7)) & 7) << 4));
      }
    }
    #pragma unroll
    for (int n = 0; n < 2; ++n) {
      const int r = wc * 32 + n * 16 + lrow;
      #pragma unroll
      for (int kk = 0; kk < 2; ++kk) {
        const int kb = lkb + kk * 4;
        bf[n][kk] = *(const bf16x8*)(VsB + r * 128 + (((kb ^ (r & 7)) & 7) << 4));
      }
    }
    #pragma unroll
    for (int m = 0; m < 2; ++m)
      #pragma unroll
      for (int n = 0; n < 2; ++n) {
        acc[m][n] = __builtin_amdgcn_mfma_f32_16x16x32_bf16(af[m][0], bf[n][0], acc[m][n], 0, 0, 0);
        acc[m][n] = __builtin_amdgcn_mfma_f32_16x16x32_bf16(af[m][1], bf[n][1], acc[m][n], 0, 0, 0);
      }
    if (wc == 0) {
      #pragma unroll
      for (int m = 0; m < 2; ++m)
        #pragma unroll
        for (int kk = 0; kk < 2; ++kk)
          #pragma unroll
          for (int j = 0; j < 8; ++j) ksf[m] += (float)af[m][kk][j];
    }
    __syncthreads();
    cur ^= 1;
  }

  float* kvp = kv + (size_t)bh * 4096;
  #pragma unroll
  for (int m = 0; m < 2; ++m)
    #pragma unroll
    for (int n = 0; n < 2; ++n)
      #pragma unroll
      for (int j = 0; j < 4; ++j)
        atomicAdd(&kvp[(wr * 32 + m * 16 + lkb * 4 + j) * 64 + wc * 32 + n * 16 + lrow],
                  acc[m][n][j]);
  if (wc == 0) {
    #pragma unroll
    for (int m = 0; m < 2; ++m) {
      float s = ksf[m];
      s += __shfl_xor(s, 16);
      s += __shfl_xor(s, 32);
      if (l < 16) atomicAdd(&ksum[(size_t)bh * 64 + wr * 32 + m * 16 + l], s);
    }
  }
}

// ---------------- W2T[b][j][h*64+f] = sum_d kv[b,h,f,d] * w_proj[h*64+d][j] ----------------
__global__ __launch_bounds__(256) void w2_kernel(const float* __restrict__ kv,
                                                 const float* __restrict__ w_proj,
                                                 bf16_t* __restrict__ W2T) {
  const int bh = blockIdx.x, b = bh >> 3, h = bh & 7;
  const int j0 = blockIdx.y * 64;
  const int t = threadIdx.x;
  __shared__ float kvs[64][64];
  __shared__ float wps[64][64];
  const float* kvp = kv + (size_t)bh * 4096;
  #pragma unroll
  for (int i = 0; i < 16; ++i) ((float*)kvs)[t + 256 * i] = kvp[t + 256 * i];
  {
    const int d = t >> 2, c16 = (t & 3) * 16;
    const float* src = w_proj + (size_t)(h * 64 + d) * 512 + j0 + c16;
    #pragma unroll
    for (int j = 0; j < 16; ++j) wps[d][c16 + j] = src[j];
  }
  __syncthreads();
  const int fq = t >> 4, jq = t & 15;
  float acc[4][4] = {};
  for (int d = 0; d < 64; ++d) {
    float kf[4], wj[4];
    #pragma unroll
    for (int i = 0; i < 4; ++i) kf[i] = kvs[fq * 4 + i][d];
    #pragma unroll
    for (int i = 0; i < 4; ++i) wj[i] = wps[d][jq * 4 + i];
    #pragma unroll
    for (int i = 0; i < 4; ++i)
      #pragma unroll
      for (int j = 0; j < 4; ++j) acc[i][j] += kf[i] * wj[j];
  }
  #pragma unroll
  for (int j = 0; j < 4; ++j)
    #pragma unroll
    for (int i = 0; i < 4; ++i)
      W2T[((size_t)b * 512 + j0 + jq * 4 + j) * 512 + h * 64 + fq * 4 + i] = (bf16_t)acc[i][j];
}

// ==================== output GEMM: fused z-scale (zq) in B-staging ====================
__global__ __launch_bounds__(256) void gemm_out(const bf16_t* __restrict__ W2T,
                                                const bf16_t* __restrict__ q_phi,
                                                const float* __restrict__ ksum,
                                                float* __restrict__ Cout,
                                                const float* __restrict__ bias) {
  __shared__ alignas(16) char smem[67584];  // A [0,32K) x2; B [32K,64K) x2; ksum [64K,66K)
  const int t = threadIdx.x, w = t >> 6, l = t & 63;
  const int hw = blockIdx.x;
  const int bid = (hw & 7) * 128 + (hw >> 3);   // 1024/8=128
  const int z = bid >> 7;
  const int rem = bid & 127;
  const int qblk = rem >> 2, pblk = rem & 3;
  const size_t tok0 = (size_t)qblk * 128;
  const int pj0 = pblk * 128;
  const bf16_t* Pp = W2T + ((size_t)z * 512 + pj0) * 512;

  const int wr = w >> 1, wc = w & 1;
  const int lrow = l & 15, lkb = l >> 4;
  const int st_r = l >> 3;
  const int st_c = ((l & 7) ^ st_r) * 8;
  const int token = t >> 1, half = t & 1;
  float* ks_lds = (float*)(smem + 65536);

  bf16x8 breg[4];
  auto loadB = [&](int c) {
    const bf16_t* p = q_phi + ((size_t)z * 4096 + tok0 + token) * 512 + c * 64 + half * 32;
    breg[0] = *(const bf16x8*)p;
    breg[1] = *(const bf16x8*)(p + 8);
    breg[2] = *(const bf16x8*)(p + 16);
    breg[3] = *(const bf16x8*)(p + 24);
  };
  auto stageA = [&](int s) {
    #pragma unroll
    for (int c = 0; c < 4; ++c) {
      const int q8 = c * 4 + w;
      gload16(Pp + (size_t)(q8 * 8 + st_r) * 512 + s * 64 + st_c,
              smem + (s & 1) * 16384 + q8 * 1024);
    }
  };
  auto procB = [&](int c) {
    const f32x4* ksv = (const f32x4*)(ks_lds + c * 64 + half * 32);
    float vals[32];
    float dot = 0.f;
    #pragma unroll
    for (int g = 0; g < 8; ++g) {
      const f32x4 kk = ksv[g];
      #pragma unroll
      for (int j = 0; j < 4; ++j) {
        const float v = (float)breg[g >> 1][(g & 1) * 4 + j];
        vals[g * 4 + j] = v;
        dot += v * kk[j];
      }
    }
    dot += __shfl_xor(dot, 1);  // lanes 2i,2i+1 share a token
    const float zz = 1.f / dot;
    char* dst = smem + 32768 + (c & 1) * 16384;
    #pragma unroll
    for (int g = 0; g < 4; ++g) {
      bf16x8 o;
      #pragma unroll
      for (int j = 0; j < 8; ++j) o[j] = (bf16_t)(vals[g * 8 + j] * zz);
      const int uk = half * 4 + g;
      *(bf16x8*)(dst + token * 128 + ((uk ^ (token & 7)) << 4)) = o;
    }
  };

  // prologue: ksum -> LDS; then chunk 0 staged
  {
    const f32x2 kk = *(const f32x2*)&ksum[(size_t)z * 512 + t * 2];
    *(f32x2*)&ks_lds[t * 2] = kk;
  }
  __syncthreads();
  loadB(0);
  stageA(0);
  procB(0);
  VMW(0);
  __syncthreads();

  f32x4 acc[4][4];
  #pragma unroll
  for (int m = 0; m < 4; ++m)
    #pragma unroll
    for (int n = 0; n < 4; ++n) acc[m][n] = f32x4{0.f, 0.f, 0.f, 0.f};

  for (int kt = 0; kt < 8; ++kt) {
    const char* PsB = smem + (kt & 1) * 16384;
    const char* QsB = smem + 32768 + (kt & 1) * 16384;
    bf16x8 pf[4][2], qf[4][2];
    #pragma unroll
    for (int m = 0; m < 4; ++m) {
      const int r = wr * 64 + m * 16 + lrow;
      #pragma unroll
      for (int kk = 0; kk < 2; ++kk) {
        const int kb = lkb + kk * 4;
        pf[m][kk] = *(const bf16x8*)(PsB + r * 128 + (((kb ^ (r & 7)) & 7) << 4));
      }
    }
    #pragma unroll
    for (int n = 0; n < 4; ++n) {
      const int r = wc * 64 + n * 16 + lrow;
      #pragma unroll
      for (int kk = 0; kk < 2; ++kk) {
        const int kb = lkb + kk * 4;
        qf[n][kk] = *(const bf16x8*)(QsB + r * 128 + (((kb ^ (r & 7)) & 7) << 4));
      }
    }
    if (kt + 1 < 8) { loadB(kt + 1); stageA(kt + 1); }
    #pragma unroll
    for (int m = 0; m < 4; ++m)
      #pragma unroll
      for (int n = 0; n < 4; ++n) {
        acc[m][n] = __builtin_amdgcn_mfma_f32_16x16x32_bf16(pf[m][0], qf[n][0], acc[m][n], 0, 0, 0);
        acc[m][n] = __builtin_amdgcn_mfma_f32_16x16x32_bf16(pf[m][1], qf[n][1], acc[m][n], 0, 0, 0);
      }
    if (kt + 1 < 8) { procB(kt + 1); VMW(0); }
    __syncthreads();
  }

  // epilogue: two phases of [64 token-rows][128 j] f32 (32 KB each) in smem[0,32K)
  float* ep = (float*)smem;
  #pragma unroll
  for (int p = 0; p < 2; ++p) {
    if (p) __syncthreads();
    #pragma unroll
    for (int nn2 = 0; nn2 < 2; ++nn2) {
      const int n = p * 2 + nn2;
      const int r6 = wc * 32 + (n & 1) * 16 + lrow;
      #pragma unroll
      for (int m = 0; m < 4; ++m) {
        const int pr0 = wr * 64 + m * 16 + lkb * 4;
        f32x4 v = acc[m][n];
        const f32x4 bv = *(const f32x4*)&bias[pj0 + pr0];
        #pragma unroll
        for (int j = 0; j < 4; ++j) v[j] += bv[j];
        const int u = pr0 >> 2;
        *(f32x4*)((char*)ep + r6 * 512 + ((u ^ (r6 & 31)) << 4)) = v;
      }
    }
    __syncthreads();
    #pragma unroll
    for (int i = 0; i < 8; ++i) {
      const int flat = i * 256 + t;
      const int r6 = flat >> 5, u2 = flat & 31;
      f32x4 v = *(const f32x4*)((char*)ep + r6 * 512 + ((u2 ^ (r6 & 31)) << 4));
      const int qc = (r6 >> 5) * 64 + p * 32 + (r6 & 31);
      *(f32x4*)&Cout[((size_t)z * 4096 + tok0 + qc) * 512 + pj0 + u2 * 4] = v;
    }
  }
}

extern "C" void kernel_launch(void* const* d_in, const int* in_sizes, int n_in,
                              void* d_out, int out_size, void* d_ws, size_t ws_size,
                              hipStream_t stream) {
  const float* x      = (const float*)d_in[0];
  const float* w_qkv  = (const float*)d_in[1];
  const float* proj   = (const float*)d_in[2];
  const float* w_proj = (const float*)d_in[3];
  const float* b_proj = (const float*)d_in[4];
  float* out = (float*)d_out;
  char* ws = (char*)d_ws;

  // workspace layout (bytes)
  bf16_t* WeffT = (bf16_t*)(ws + 0);           // 1536*512*2   =  1,572,864
  bf16_t* q_phi = (bf16_t*)(ws + 1572864);     // 32768*512*2  = 33,554,432
  bf16_t* kT    = (bf16_t*)(ws + 35127296);    // 64*64*4096*2 = 33,554,432
  bf16_t* vT    = (bf16_t*)(ws + 68681728);    // 64*64*4096*2 = 33,554,432
  float*  kv    = (float*)(ws + 102236160);    // 64*64*64*4   =  1,048,576
  float*  ksum  = (float*)(ws + 103284736);    // 64*64*4      =     16,384
  bf16_t* W2T   = (bf16_t*)(ws + 103301120);   // 8*512*512*2  =  4,194,304
                                               // total 107,495,424

  prep_qk<<<dim3(16, 8), 256, 0, stream>>>(w_qkv, proj, WeffT);
  prep_v<<<dim3(16, 16), 256, 0, stream>>>(w_qkv, WeffT);
  gemm_qkv<<<3072, 256, 0, stream>>>(x, WeffT, q_phi, kT, vT);
  hipMemsetAsync(kv, 0, 1048576 + 16384, stream);
  kv_mfma<<<dim3(64, 8), 256, 0, stream>>>(kT, vT, kv, ksum);
  w2_kernel<<<dim3(64, 8), 256, 0, stream>>>(kv, w_proj, W2T);
  gemm_out<<<1024, 256, 0, stream>>>(W2T, q_phi, ksum, out, b_proj);
}

// Round 15
// 169.810 us; speedup vs baseline: 2.0396x; 2.0396x over previous
//
#include <hip/hip_runtime.h>
#include <hip/hip_bf16.h>

typedef __bf16 bf16_t;
typedef __bf16 bf16x4 __attribute__((ext_vector_type(4)));
typedef __bf16 bf16x8 __attribute__((ext_vector_type(8)));
typedef float f32x2 __attribute__((ext_vector_type(2)));
typedef float f32x4 __attribute__((ext_vector_type(4)));

__device__ __forceinline__ void gload16(const void* g, void* l) {
  __builtin_amdgcn_global_load_lds((const __attribute__((address_space(1))) void*)g,
                                   (__attribute__((address_space(3))) void*)l, 16, 0, 0);
}

#define VMW(n) asm volatile("s_waitcnt vmcnt(" #n ")" ::: "memory")

// ---------------- prep: fold proj into w_qkv (q,k halves) ----------------
__global__ __launch_bounds__(256) void prep_qk(const float* __restrict__ w_qkv,
                                               const float* __restrict__ proj,
                                               bf16_t* __restrict__ WeffT) {
  const int half = blockIdx.x >> 3, h = blockIdx.x & 7;
  const int i0 = blockIdx.y * 64;
  __shared__ float P[64 * 64];   // [d][f] == proj[h] layout
  __shared__ float Wt[64][65];   // [ii][d], padded
  const int t = threadIdx.x;
  #pragma unroll
  for (int r = 0; r < 16; ++r) P[t + 256 * r] = proj[(size_t)h * 4096 + t + 256 * r];
  #pragma unroll
  for (int r = 0; r < 16; ++r) {
    const int idx = t + 256 * r;
    Wt[idx >> 6][idx & 63] =
        w_qkv[(size_t)(i0 + (idx >> 6)) * 1536 + half * 512 + h * 64 + (idx & 63)];
  }
  __syncthreads();
  const int i = t & 63, fg = t >> 6;
  for (int f = fg; f < 64; f += 4) {
    float s = 0.f;
    #pragma unroll
    for (int d = 0; d < 64; ++d) s += Wt[i][d] * P[d * 64 + f];
    WeffT[(size_t)(half * 512 + h * 64 + f) * 512 + i0 + i] = (bf16_t)s;
  }
}

// ---------------- prep: v passthrough transpose ----------------
__global__ __launch_bounds__(256) void prep_v(const float* __restrict__ w_qkv,
                                              bf16_t* __restrict__ WeffT) {
  __shared__ bf16_t tile[32][33];
  const int i0 = blockIdx.x * 32, n0 = blockIdx.y * 32;
  const int tn = threadIdx.x & 31, ti = threadIdx.x >> 5;
  #pragma unroll
  for (int p = 0; p < 4; ++p) {
    const int i = ti + p * 8;
    tile[i][tn] = (bf16_t)w_qkv[(size_t)(i0 + i) * 1536 + 1024 + n0 + tn];
  }
  __syncthreads();
  #pragma unroll
  for (int p = 0; p < 4; ++p) {
    const int n = ti + p * 8;
    WeffT[(size_t)(1024 + n0 + n) * 512 + i0 + tn] = tile[tn][n];
  }
}

// ==================== merged QKV GEMM v5: f32 x staged via gload_lds ====================
// R4 fenced skeleton (proven replay-safe), BK=32, 16 K-steps, __syncthreads/step.
// 3072 blocks 1-D, XCD-chunked. bid -> (tok_blk = bid/12, cb = bid%12).
// cb<4:  q path. P=WeffT rows [cb*128) (bf16 tile H), Q=x tokens (f32 tile F).
// cb>=4: kv path. P=x tokens (F), Q=WeffT rows [512+(cb-4)*128) (H).
// F: [128 tok][32 k] f32, 16KB/buf, unit swizzle u^=(row&7)  (2-way, free).
// H: [128 ft][32 k] bf16,  8KB/buf, unit swizzle u^=((row>>1)&3) (2-way).
// x is converted f32->bf16 at fragment-read time (same RNE cast as cast_x did).
// LDS 48KB -> 3 blocks/CU.
__global__ __launch_bounds__(256) void gemm_qkv(const float* __restrict__ x,
                                                const bf16_t* __restrict__ WeffT,
                                                bf16_t* __restrict__ q_phi,
                                                bf16_t* __restrict__ kT,
                                                bf16_t* __restrict__ vT) {
  __shared__ alignas(16) char smem[49152];  // F [0,32K) x2; H [32K,48K) x2
  const int t = threadIdx.x, w = t >> 6, l = t & 63;
  const int hw = blockIdx.x;
  const int bid = (hw & 7) * 384 + (hw >> 3);   // XCD-chunked (3072/8=384)
  const int tok_blk = bid / 12, cb = bid % 12;
  const size_t tok0 = (size_t)tok_blk * 128;
  const bool qpath = (cb < 4);
  const float* Xp = x + tok0 * 512;
  const bf16_t* Wp = WeffT + (size_t)(qpath ? cb * 128 : 512 + (cb - 4) * 128) * 512;

  const int wr = w >> 1, wc = w & 1;
  const int lrow = l & 15, lkb = l >> 4;

  // staging geometry
  const int sr8 = t >> 3, su8 = t & 7;  // F tile: row c*32+sr8, 16B unit su8
  const int sr4 = t >> 2, su4 = t & 3;  // H tile: row c*64+sr4, 16B unit su4
  const size_t fcol = (size_t)((su8 ^ (sr8 & 7)) * 4);        // f32 units of 4
  const size_t hcol = (size_t)((su4 ^ ((t >> 3) & 3)) * 8);   // bf16 units of 8

  auto stageF = [&](int s) {
    char* dst = smem + (s & 1) * 16384;
    #pragma unroll
    for (int c = 0; c < 4; ++c)
      gload16(Xp + (size_t)(c * 32 + sr8) * 512 + s * 32 + fcol, dst + c * 4096 + t * 16);
  };
  auto stageH = [&](int s) {
    char* dst = smem + 32768 + (s & 1) * 8192;
    #pragma unroll
    for (int c = 0; c < 2; ++c)
      gload16(Wp + (size_t)(c * 64 + sr4) * 512 + s * 32 + hcol, dst + c * 4096 + t * 16);
  };

  f32x4 acc[4][4];
  #pragma unroll
  for (int m = 0; m < 4; ++m)
    #pragma unroll
    for (int n = 0; n < 4; ++n) acc[m][n] = f32x4{0.f, 0.f, 0.f, 0.f};

  // prologue: tile 0 into buf 0; barrier drains (implicit vmcnt(0))
  stageF(0); stageH(0);
  __syncthreads();

  for (int kt = 0; kt < 16; ++kt) {
    if (kt + 1 < 16) { stageF(kt + 1); stageH(kt + 1); }  // prefetch into other buf
    const char* Fs = smem + (kt & 1) * 16384;
    const char* Hs = smem + 32768 + (kt & 1) * 8192;
    bf16x8 pf[4], qf[4];
    if (qpath) {
      #pragma unroll
      for (int m = 0; m < 4; ++m) {
        const int r = wr * 64 + m * 16 + lrow;  // WeffT rows
        pf[m] = *(const bf16x8*)(Hs + r * 64 + ((lkb ^ ((r >> 1) & 3)) << 4));
      }
      #pragma unroll
      for (int n = 0; n < 4; ++n) {
        const int r = wc * 64 + n * 16 + lrow;  // token rows
        const f32x4 a = *(const f32x4*)(Fs + r * 128 + (((2 * lkb) ^ (r & 7)) << 4));
        const f32x4 b = *(const f32x4*)(Fs + r * 128 + (((2 * lkb + 1) ^ (r & 7)) << 4));
        #pragma unroll
        for (int j = 0; j < 4; ++j) { qf[n][j] = (bf16_t)a[j]; qf[n][4 + j] = (bf16_t)b[j]; }
      }
    } else {
      #pragma unroll
      for (int m = 0; m < 4; ++m) {
        const int r = wr * 64 + m * 16 + lrow;  // token rows
        const f32x4 a = *(const f32x4*)(Fs + r * 128 + (((2 * lkb) ^ (r & 7)) << 4));
        const f32x4 b = *(const f32x4*)(Fs + r * 128 + (((2 * lkb + 1) ^ (r & 7)) << 4));
        #pragma unroll
        for (int j = 0; j < 4; ++j) { pf[m][j] = (bf16_t)a[j]; pf[m][4 + j] = (bf16_t)b[j]; }
      }
      #pragma unroll
      for (int n = 0; n < 4; ++n) {
        const int r = wc * 64 + n * 16 + lrow;  // WeffT rows
        qf[n] = *(const bf16x8*)(Hs + r * 64 + ((lkb ^ ((r >> 1) & 3)) << 4));
      }
    }
    #pragma unroll
    for (int m = 0; m < 4; ++m)
      #pragma unroll
      for (int n = 0; n < 4; ++n)
        acc[m][n] = __builtin_amdgcn_mfma_f32_16x16x32_bf16(pf[m], qf[n], acc[m][n], 0, 0, 0);
    __syncthreads();  // readers done with cur; prefetch landed (drain)
  }

  // ---- epilogue: restage tile [128 qrows][128 prows] bf16 in LDS, coalesced store ----
  bf16_t* ep = (bf16_t*)smem;  // 32 KB, rows 256 B, 16-B-unit XOR swizzle
  const bool doElu = qpath || (cb < 8);  // q and k get elu+1; v passthrough
  #pragma unroll
  for (int n = 0; n < 4; ++n) {
    const int qc = wc * 64 + n * 16 + lrow;
    #pragma unroll
    for (int m = 0; m < 4; ++m) {
      const int pr0 = wr * 64 + m * 16 + lkb * 4;
      bf16x4 o;
      #pragma unroll
      for (int j = 0; j < 4; ++j) {
        float v = acc[m][n][j];
        if (doElu) v = v > 0.f ? v + 1.f : __expf(v);
        o[j] = (bf16_t)v;
      }
      const int u = pr0 >> 3;
      *(bf16x4*)((char*)ep + qc * 256 + ((u ^ (qc & 15)) << 4) + (pr0 & 7) * 2) = o;
    }
  }
  __syncthreads();
  #pragma unroll
  for (int i = 0; i < 8; ++i) {
    const int flat = i * 256 + t;
    const int qc2 = flat >> 4, u2 = flat & 15;
    bf16x8 vv = *(const bf16x8*)((char*)ep + qc2 * 256 + ((u2 ^ (qc2 & 15)) << 4));
    if (qpath) {
      *(bf16x8*)&q_phi[(tok0 + qc2) * 512 + cb * 128 + u2 * 8] = vv;
    } else {
      const int f512 = (cb - 4) * 128 + qc2;  // 0..1023: k then v
      bf16_t* dst = (f512 < 512 ? kT + ((size_t)(tok0 >> 12) * 512 + f512) * 4096
                                : vT + ((size_t)(tok0 >> 12) * 512 + (f512 - 512)) * 4096) +
                    (tok0 & 4095) + u2 * 8;
      *(bf16x8*)dst = vv;
    }
  }
}

// ---------------- kv[f][d] = sum_n kT[f][n]*vT[d][n]; ksum[f] = sum_n kT[f][n] ----
__global__ __launch_bounds__(256) void kv_mfma(const bf16_t* __restrict__ kT,
                                               const bf16_t* __restrict__ vT,
                                               float* __restrict__ kv,
                                               float* __restrict__ ksum) {
  const int bh = blockIdx.x;
  const int nbase = blockIdx.y * 512;
  __shared__ alignas(16) char smem[32768];  // 2 bufs x (K 8K + V 8K)
  const int t = threadIdx.x, w = t >> 6, l = t & 63;
  const int wr = w >> 1, wc = w & 1;
  const int lrow = l & 15, lkb = l >> 4;
  const int st_r = l >> 3;
  const int st_c = ((l & 7) ^ st_r) * 8;
  const bf16_t* Kp = kT + (size_t)bh * 64 * 4096;
  const bf16_t* Vp = vT + (size_t)bh * 64 * 4096;

  f32x4 acc[2][2];
  #pragma unroll
  for (int m = 0; m < 2; ++m)
    #pragma unroll
    for (int n = 0; n < 2; ++n) acc[m][n] = f32x4{0.f, 0.f, 0.f, 0.f};
  float ksf[2] = {0.f, 0.f};

  #pragma unroll
  for (int c = 0; c < 2; ++c) {
    const int q8 = w * 2 + c;
    gload16(Kp + (size_t)(q8 * 8 + st_r) * 4096 + nbase + st_c, smem + q8 * 1024);
    gload16(Vp + (size_t)(q8 * 8 + st_r) * 4096 + nbase + st_c, smem + 8192 + q8 * 1024);
  }
  __syncthreads();

  int cur = 0;
  for (int st = 0; st < 8; ++st) {
    if (st < 7) {
      char* nb = smem + (cur ^ 1) * 16384;
      const int nb2 = nbase + (st + 1) * 64;
      #pragma unroll
      for (int c = 0; c < 2; ++c) {
        const int q8 = w * 2 + c;
        gload16(Kp + (size_t)(q8 * 8 + st_r) * 4096 + nb2 + st_c, nb + q8 * 1024);
        gload16(Vp + (size_t)(q8 * 8 + st_r) * 4096 + nb2 + st_c, nb + 8192 + q8 * 1024);
      }
    }
    const char* KsB = smem + cur * 16384;
    const char* VsB = KsB + 8192;
    bf16x8 af[2][2], bf[2][2];
    #pragma unroll
    for (int m = 0; m < 2; ++m) {
      const int r = wr * 32 + m * 16 + lrow;
      #pragma unroll
      for (int kk = 0; kk < 2; ++kk) {
        const int kb = lkb + kk * 4;
        af[m][kk] = *(const bf16x8*)(KsB + r * 128 + (((kb ^ (r & 7)) & 7) << 4));
      }
    }
    #pragma unroll
    for (int n = 0; n < 2; ++n) {
      const int r = wc * 32 + n * 16 + lrow;
      #pragma unroll
      for (int kk = 0; kk < 2; ++kk) {
        const int kb = lkb + kk * 4;
        bf[n][kk] = *(const bf16x8*)(VsB + r * 128 + (((kb ^ (r & 7)) & 7) << 4));
      }
    }
    #pragma unroll
    for (int m = 0; m < 2; ++m)
      #pragma unroll
      for (int n = 0; n < 2; ++n) {
        acc[m][n] = __builtin_amdgcn_mfma_f32_16x16x32_bf16(af[m][0], bf[n][0], acc[m][n], 0, 0, 0);
        acc[m][n] = __builtin_amdgcn_mfma_f32_16x16x32_bf16(af[m][1], bf[n][1], acc[m][n], 0, 0, 0);
      }
    if (wc == 0) {
      #pragma unroll
      for (int m = 0; m < 2; ++m)
        #pragma unroll
        for (int kk = 0; kk < 2; ++kk)
          #pragma unroll
          for (int j = 0; j < 8; ++j) ksf[m] += (float)af[m][kk][j];
    }
    __syncthreads();
    cur ^= 1;
  }

  float* kvp = kv + (size_t)bh * 4096;
  #pragma unroll
  for (int m = 0; m < 2; ++m)
    #pragma unroll
    for (int n = 0; n < 2; ++n)
      #pragma unroll
      for (int j = 0; j < 4; ++j)
        atomicAdd(&kvp[(wr * 32 + m * 16 + lkb * 4 + j) * 64 + wc * 32 + n * 16 + lrow],
                  acc[m][n][j]);
  if (wc == 0) {
    #pragma unroll
    for (int m = 0; m < 2; ++m) {
      float s = ksf[m];
      s += __shfl_xor(s, 16);
      s += __shfl_xor(s, 32);
      if (l < 16) atomicAdd(&ksum[(size_t)bh * 64 + wr * 32 + m * 16 + l], s);
    }
  }
}

// ---------------- W2T[b][j][h*64+f] = sum_d kv[b,h,f,d] * w_proj[h*64+d][j] ----------------
__global__ __launch_bounds__(256) void w2_kernel(const float* __restrict__ kv,
                                                 const float* __restrict__ w_proj,
                                                 bf16_t* __restrict__ W2T) {
  const int bh = blockIdx.x, b = bh >> 3, h = bh & 7;
  const int j0 = blockIdx.y * 64;
  const int t = threadIdx.x;
  __shared__ float kvs[64][64];
  __shared__ float wps[64][64];
  const float* kvp = kv + (size_t)bh * 4096;
  #pragma unroll
  for (int i = 0; i < 16; ++i) ((float*)kvs)[t + 256 * i] = kvp[t + 256 * i];
  {
    const int d = t >> 2, c16 = (t & 3) * 16;
    const float* src = w_proj + (size_t)(h * 64 + d) * 512 + j0 + c16;
    #pragma unroll
    for (int j = 0; j < 16; ++j) wps[d][c16 + j] = src[j];
  }
  __syncthreads();
  const int fq = t >> 4, jq = t & 15;
  float acc[4][4] = {};
  for (int d = 0; d < 64; ++d) {
    float kf[4], wj[4];
    #pragma unroll
    for (int i = 0; i < 4; ++i) kf[i] = kvs[fq * 4 + i][d];
    #pragma unroll
    for (int i = 0; i < 4; ++i) wj[i] = wps[d][jq * 4 + i];
    #pragma unroll
    for (int i = 0; i < 4; ++i)
      #pragma unroll
      for (int j = 0; j < 4; ++j) acc[i][j] += kf[i] * wj[j];
  }
  #pragma unroll
  for (int j = 0; j < 4; ++j)
    #pragma unroll
    for (int i = 0; i < 4; ++i)
      W2T[((size_t)b * 512 + j0 + jq * 4 + j) * 512 + h * 64 + fq * 4 + i] = (bf16_t)acc[i][j];
}

// ==================== output GEMM: fused z-scale (zq) in B-staging ====================
__global__ __launch_bounds__(256) void gemm_out(const bf16_t* __restrict__ W2T,
                                                const bf16_t* __restrict__ q_phi,
                                                const float* __restrict__ ksum,
                                                float* __restrict__ Cout,
                                                const float* __restrict__ bias) {
  __shared__ alignas(16) char smem[67584];  // A [0,32K) x2; B [32K,64K) x2; ksum [64K,66K)
  const int t = threadIdx.x, w = t >> 6, l = t & 63;
  const int hw = blockIdx.x;
  const int bid = (hw & 7) * 128 + (hw >> 3);   // 1024/8=128
  const int z = bid >> 7;
  const int rem = bid & 127;
  const int qblk = rem >> 2, pblk = rem & 3;
  const size_t tok0 = (size_t)qblk * 128;
  const int pj0 = pblk * 128;
  const bf16_t* Pp = W2T + ((size_t)z * 512 + pj0) * 512;

  const int wr = w >> 1, wc = w & 1;
  const int lrow = l & 15, lkb = l >> 4;
  const int st_r = l >> 3;
  const int st_c = ((l & 7) ^ st_r) * 8;
  const int token = t >> 1, half = t & 1;
  float* ks_lds = (float*)(smem + 65536);

  bf16x8 breg[4];
  auto loadB = [&](int c) {
    const bf16_t* p = q_phi + ((size_t)z * 4096 + tok0 + token) * 512 + c * 64 + half * 32;
    breg[0] = *(const bf16x8*)p;
    breg[1] = *(const bf16x8*)(p + 8);
    breg[2] = *(const bf16x8*)(p + 16);
    breg[3] = *(const bf16x8*)(p + 24);
  };
  auto stageA = [&](int s) {
    #pragma unroll
    for (int c = 0; c < 4; ++c) {
      const int q8 = c * 4 + w;
      gload16(Pp + (size_t)(q8 * 8 + st_r) * 512 + s * 64 + st_c,
              smem + (s & 1) * 16384 + q8 * 1024);
    }
  };
  auto procB = [&](int c) {
    const f32x4* ksv = (const f32x4*)(ks_lds + c * 64 + half * 32);
    float vals[32];
    float dot = 0.f;
    #pragma unroll
    for (int g = 0; g < 8; ++g) {
      const f32x4 kk = ksv[g];
      #pragma unroll
      for (int j = 0; j < 4; ++j) {
        const float v = (float)breg[g >> 1][(g & 1) * 4 + j];
        vals[g * 4 + j] = v;
        dot += v * kk[j];
      }
    }
    dot += __shfl_xor(dot, 1);  // lanes 2i,2i+1 share a token
    const float zz = 1.f / dot;
    char* dst = smem + 32768 + (c & 1) * 16384;
    #pragma unroll
    for (int g = 0; g < 4; ++g) {
      bf16x8 o;
      #pragma unroll
      for (int j = 0; j < 8; ++j) o[j] = (bf16_t)(vals[g * 8 + j] * zz);
      const int uk = half * 4 + g;
      *(bf16x8*)(dst + token * 128 + ((uk ^ (token & 7)) << 4)) = o;
    }
  };

  // prologue: ksum -> LDS; then chunk 0 staged
  {
    const f32x2 kk = *(const f32x2*)&ksum[(size_t)z * 512 + t * 2];
    *(f32x2*)&ks_lds[t * 2] = kk;
  }
  __syncthreads();
  loadB(0);
  stageA(0);
  procB(0);
  VMW(0);
  __syncthreads();

  f32x4 acc[4][4];
  #pragma unroll
  for (int m = 0; m < 4; ++m)
    #pragma unroll
    for (int n = 0; n < 4; ++n) acc[m][n] = f32x4{0.f, 0.f, 0.f, 0.f};

  for (int kt = 0; kt < 8; ++kt) {
    const char* PsB = smem + (kt & 1) * 16384;
    const char* QsB = smem + 32768 + (kt & 1) * 16384;
    bf16x8 pf[4][2], qf[4][2];
    #pragma unroll
    for (int m = 0; m < 4; ++m) {
      const int r = wr * 64 + m * 16 + lrow;
      #pragma unroll
      for (int kk = 0; kk < 2; ++kk) {
        const int kb = lkb + kk * 4;
        pf[m][kk] = *(const bf16x8*)(PsB + r * 128 + (((kb ^ (r & 7)) & 7) << 4));
      }
    }
    #pragma unroll
    for (int n = 0; n < 4; ++n) {
      const int r = wc * 64 + n * 16 + lrow;
      #pragma unroll
      for (int kk = 0; kk < 2; ++kk) {
        const int kb = lkb + kk * 4;
        qf[n][kk] = *(const bf16x8*)(QsB + r * 128 + (((kb ^ (r & 7)) & 7) << 4));
      }
    }
    if (kt + 1 < 8) { loadB(kt + 1); stageA(kt + 1); }
    #pragma unroll
    for (int m = 0; m < 4; ++m)
      #pragma unroll
      for (int n = 0; n < 4; ++n) {
        acc[m][n] = __builtin_amdgcn_mfma_f32_16x16x32_bf16(pf[m][0], qf[n][0], acc[m][n], 0, 0, 0);
        acc[m][n] = __builtin_amdgcn_mfma_f32_16x16x32_bf16(pf[m][1], qf[n][1], acc[m][n], 0, 0, 0);
      }
    if (kt + 1 < 8) { procB(kt + 1); VMW(0); }
    __syncthreads();
  }

  // epilogue: two phases of [64 token-rows][128 j] f32 (32 KB each) in smem[0,32K)
  float* ep = (float*)smem;
  #pragma unroll
  for (int p = 0; p < 2; ++p) {
    if (p) __syncthreads();
    #pragma unroll
    for (int nn2 = 0; nn2 < 2; ++nn2) {
      const int n = p * 2 + nn2;
      const int r6 = wc * 32 + (n & 1) * 16 + lrow;
      #pragma unroll
      for (int m = 0; m < 4; ++m) {
        const int pr0 = wr * 64 + m * 16 + lkb * 4;
        f32x4 v = acc[m][n];
        const f32x4 bv = *(const f32x4*)&bias[pj0 + pr0];
        #pragma unroll
        for (int j = 0; j < 4; ++j) v[j] += bv[j];
        const int u = pr0 >> 2;
        *(f32x4*)((char*)ep + r6 * 512 + ((u ^ (r6 & 31)) << 4)) = v;
      }
    }
    __syncthreads();
    #pragma unroll
    for (int i = 0; i < 8; ++i) {
      const int flat = i * 256 + t;
      const int r6 = flat >> 5, u2 = flat & 31;
      f32x4 v = *(const f32x4*)((char*)ep + r6 * 512 + ((u2 ^ (r6 & 31)) << 4));
      const int qc = (r6 >> 5) * 64 + p * 32 + (r6 & 31);
      *(f32x4*)&Cout[((size_t)z * 4096 + tok0 + qc) * 512 + pj0 + u2 * 4] = v;
    }
  }
}

extern "C" void kernel_launch(void* const* d_in, const int* in_sizes, int n_in,
                              void* d_out, int out_size, void* d_ws, size_t ws_size,
                              hipStream_t stream) {
  const float* x      = (const float*)d_in[0];
  const float* w_qkv  = (const float*)d_in[1];
  const float* proj   = (const float*)d_in[2];
  const float* w_proj = (const float*)d_in[3];
  const float* b_proj = (const float*)d_in[4];
  float* out = (float*)d_out;
  char* ws = (char*)d_ws;

  // workspace layout (bytes)
  bf16_t* WeffT = (bf16_t*)(ws + 0);           // 1536*512*2   =  1,572,864
  bf16_t* q_phi = (bf16_t*)(ws + 1572864);     // 32768*512*2  = 33,554,432
  bf16_t* kT    = (bf16_t*)(ws + 35127296);    // 64*64*4096*2 = 33,554,432
  bf16_t* vT    = (bf16_t*)(ws + 68681728);    // 64*64*4096*2 = 33,554,432
  float*  kv    = (float*)(ws + 102236160);    // 64*64*64*4   =  1,048,576
  float*  ksum  = (float*)(ws + 103284736);    // 64*64*4      =     16,384
  bf16_t* W2T   = (bf16_t*)(ws + 103301120);   // 8*512*512*2  =  4,194,304
                                               // total 107,495,424

  prep_qk<<<dim3(16, 8), 256, 0, stream>>>(w_qkv, proj, WeffT);
  prep_v<<<dim3(16, 16), 256, 0, stream>>>(w_qkv, WeffT);
  gemm_qkv<<<3072, 256, 0, stream>>>(x, WeffT, q_phi, kT, vT);
  hipMemsetAsync(kv, 0, 1048576 + 16384, stream);
  kv_mfma<<<dim3(64, 8), 256, 0, stream>>>(kT, vT, kv, ksum);
  w2_kernel<<<dim3(64, 8), 256, 0, stream>>>(kv, w_proj, W2T);
  gemm_out<<<1024, 256, 0, stream>>>(W2T, q_phi, ksum, out, b_proj);
}

// Round 16
// 166.400 us; speedup vs baseline: 2.0814x; 1.0205x over previous
//
#include <hip/hip_runtime.h>
#include <hip/hip_bf16.h>

typedef __bf16 bf16_t;
typedef __bf16 bf16x4 __attribute__((ext_vector_type(4)));
typedef __bf16 bf16x8 __attribute__((ext_vector_type(8)));
typedef float f32x2 __attribute__((ext_vector_type(2)));
typedef float f32x4 __attribute__((ext_vector_type(4)));

__device__ __forceinline__ void gload16(const void* g, void* l) {
  __builtin_amdgcn_global_load_lds((const __attribute__((address_space(1))) void*)g,
                                   (__attribute__((address_space(3))) void*)l, 16, 0, 0);
}

#define VMW(n) asm volatile("s_waitcnt vmcnt(" #n ")" ::: "memory")

// ---------------- prep: fold proj into w_qkv (q,k halves) ----------------
__global__ __launch_bounds__(256) void prep_qk(const float* __restrict__ w_qkv,
                                               const float* __restrict__ proj,
                                               bf16_t* __restrict__ WeffT) {
  const int half = blockIdx.x >> 3, h = blockIdx.x & 7;
  const int i0 = blockIdx.y * 64;
  __shared__ float P[64 * 64];   // [d][f] == proj[h] layout
  __shared__ float Wt[64][65];   // [ii][d], padded
  const int t = threadIdx.x;
  #pragma unroll
  for (int r = 0; r < 16; ++r) P[t + 256 * r] = proj[(size_t)h * 4096 + t + 256 * r];
  #pragma unroll
  for (int r = 0; r < 16; ++r) {
    const int idx = t + 256 * r;
    Wt[idx >> 6][idx & 63] =
        w_qkv[(size_t)(i0 + (idx >> 6)) * 1536 + half * 512 + h * 64 + (idx & 63)];
  }
  __syncthreads();
  const int i = t & 63, fg = t >> 6;
  for (int f = fg; f < 64; f += 4) {
    float s = 0.f;
    #pragma unroll
    for (int d = 0; d < 64; ++d) s += Wt[i][d] * P[d * 64 + f];
    WeffT[(size_t)(half * 512 + h * 64 + f) * 512 + i0 + i] = (bf16_t)s;
  }
}

// ---------------- prep: v passthrough transpose ----------------
__global__ __launch_bounds__(256) void prep_v(const float* __restrict__ w_qkv,
                                              bf16_t* __restrict__ WeffT) {
  __shared__ bf16_t tile[32][33];
  const int i0 = blockIdx.x * 32, n0 = blockIdx.y * 32;
  const int tn = threadIdx.x & 31, ti = threadIdx.x >> 5;
  #pragma unroll
  for (int p = 0; p < 4; ++p) {
    const int i = ti + p * 8;
    tile[i][tn] = (bf16_t)w_qkv[(size_t)(i0 + i) * 1536 + 1024 + n0 + tn];
  }
  __syncthreads();
  #pragma unroll
  for (int p = 0; p < 4; ++p) {
    const int n = ti + p * 8;
    WeffT[(size_t)(1024 + n0 + n) * 512 + i0 + tn] = tile[tn][n];
  }
}

// ==================== merged QKV GEMM v8: kv-reduction fused into epilogue ====================
// R11/R15 verified skeleton: 3072 blocks x 256 thr, XCD-chunked, fenced __syncthreads
// per K-step, BK=32, 16 K-steps. F: x f32 [128 tok][32k] 16KB x2 (swz u^=(row&7));
// H: WeffT bf16 [128][32] 8KB x2 (swz u^=((row>>1)&3)). Main K-loop byte-identical to R15.
// NEW block map: cb<4 q path (unchanged). cb>=4: head = cb-4; H rows = [kφ-head h (64) |
// v-head h (64)] via two base pointers. kv blocks do NOT store their tile to global:
// the epilogue ep tile for kv blocks is already [feat][token] (P=x), so a second
// in-LDS MFMA stage computes partial kv[64kf][64vf] (K=128 tokens) + ksum and
// atomicAdds them (32 token-tile partials per (b,h); kv/ksum memset'd beforehand).
// This deletes kT/vT (67MB write + 67MB read) and the kv_mfma kernel entirely.
__global__ __launch_bounds__(256) void gemm_qkv(const float* __restrict__ x,
                                                const bf16_t* __restrict__ WeffT,
                                                bf16_t* __restrict__ q_phi,
                                                float* __restrict__ kv,
                                                float* __restrict__ ksum) {
  __shared__ alignas(16) char smem[49152];  // F [0,32K) x2; H [32K,48K) x2
  const int t = threadIdx.x, w = t >> 6, l = t & 63;
  const int hw = blockIdx.x;
  const int bid = (hw & 7) * 384 + (hw >> 3);   // XCD-chunked (3072/8=384)
  const int tok_blk = bid / 12, cb = bid % 12;
  const size_t tok0 = (size_t)tok_blk * 128;
  const bool qpath = (cb < 4);
  const int head = cb - 4;                      // valid for kv blocks
  const float* Xp = x + tok0 * 512;
  const bf16_t* Wp0;
  const bf16_t* Wp1;
  if (qpath) {
    Wp0 = WeffT + (size_t)cb * 128 * 512;            // q rows 0-63 of this 128-chunk
    Wp1 = Wp0 + (size_t)64 * 512;                    // q rows 64-127
  } else {
    Wp0 = WeffT + (size_t)(512 + head * 64) * 512;   // kφ-head h
    Wp1 = WeffT + (size_t)(1024 + head * 64) * 512;  // v-head h
  }

  const int wr = w >> 1, wc = w & 1;
  const int lrow = l & 15, lkb = l >> 4;

  // staging geometry (pre-swizzled global source, linear LDS dest)
  const int sr8 = t >> 3, su8 = t & 7;  // F tile: row c*32+sr8, 16B unit su8
  const int sr4 = t >> 2, su4 = t & 3;  // H tile: row (base c)+sr4, 16B unit su4
  const size_t fcol = (size_t)((su8 ^ (sr8 & 7)) * 4);        // f32 units of 4
  const size_t hcol = (size_t)((su4 ^ ((t >> 3) & 3)) * 8);   // bf16 units of 8

  auto stageF = [&](int s) {
    char* dst = smem + (s & 1) * 16384;
    #pragma unroll
    for (int c = 0; c < 4; ++c)
      gload16(Xp + (size_t)(c * 32 + sr8) * 512 + s * 32 + fcol, dst + c * 4096 + t * 16);
  };
  auto stageH = [&](int s) {
    char* dst = smem + 32768 + (s & 1) * 8192;
    gload16(Wp0 + (size_t)sr4 * 512 + s * 32 + hcol, dst + t * 16);
    gload16(Wp1 + (size_t)sr4 * 512 + s * 32 + hcol, dst + 4096 + t * 16);
  };

  f32x4 acc[4][4];
  #pragma unroll
  for (int m = 0; m < 4; ++m)
    #pragma unroll
    for (int n = 0; n < 4; ++n) acc[m][n] = f32x4{0.f, 0.f, 0.f, 0.f};

  // prologue: tile 0 into buf 0; barrier drains (implicit vmcnt(0))
  stageF(0); stageH(0);
  __syncthreads();

  for (int kt = 0; kt < 16; ++kt) {
    if (kt + 1 < 16) { stageF(kt + 1); stageH(kt + 1); }  // prefetch into other buf
    const char* Fs = smem + (kt & 1) * 16384;
    const char* Hs = smem + 32768 + (kt & 1) * 8192;
    bf16x8 pf[4], qf[4];
    if (qpath) {
      #pragma unroll
      for (int m = 0; m < 4; ++m) {
        const int r = wr * 64 + m * 16 + lrow;  // WeffT rows
        pf[m] = *(const bf16x8*)(Hs + r * 64 + ((lkb ^ ((r >> 1) & 3)) << 4));
      }
      #pragma unroll
      for (int n = 0; n < 4; ++n) {
        const int r = wc * 64 + n * 16 + lrow;  // token rows
        const f32x4 a = *(const f32x4*)(Fs + r * 128 + (((2 * lkb) ^ (r & 7)) << 4));
        const f32x4 b = *(const f32x4*)(Fs + r * 128 + (((2 * lkb + 1) ^ (r & 7)) << 4));
        #pragma unroll
        for (int j = 0; j < 4; ++j) { qf[n][j] = (bf16_t)a[j]; qf[n][4 + j] = (bf16_t)b[j]; }
      }
    } else {
      #pragma unroll
      for (int m = 0; m < 4; ++m) {
        const int r = wr * 64 + m * 16 + lrow;  // token rows
        const f32x4 a = *(const f32x4*)(Fs + r * 128 + (((2 * lkb) ^ (r & 7)) << 4));
        const f32x4 b = *(const f32x4*)(Fs + r * 128 + (((2 * lkb + 1) ^ (r & 7)) << 4));
        #pragma unroll
        for (int j = 0; j < 4; ++j) { pf[m][j] = (bf16_t)a[j]; pf[m][4 + j] = (bf16_t)b[j]; }
      }
      #pragma unroll
      for (int n = 0; n < 4; ++n) {
        const int r = wc * 64 + n * 16 + lrow;  // WeffT rows
        qf[n] = *(const bf16x8*)(Hs + r * 64 + ((lkb ^ ((r >> 1) & 3)) << 4));
      }
    }
    #pragma unroll
    for (int m = 0; m < 4; ++m)
      #pragma unroll
      for (int n = 0; n < 4; ++n)
        acc[m][n] = __builtin_amdgcn_mfma_f32_16x16x32_bf16(pf[m], qf[n], acc[m][n], 0, 0, 0);
    __syncthreads();  // readers done with cur; prefetch landed (drain)
  }

  // ---- epilogue write: ep tile [128 qrows][128 prows] bf16, 16B-unit XOR swizzle ----
  // q path: qrows=tokens, prows=feats -> ep[tok][feat]. kv path: qrows=feats (kφ 0-63,
  // v 64-127), prows=tokens -> ep[feat][tok]. elu+1 on q always; on kv only kφ rows.
  bf16_t* ep = (bf16_t*)smem;  // 32 KB, rows 256 B
  #pragma unroll
  for (int n = 0; n < 4; ++n) {
    const int qc = wc * 64 + n * 16 + lrow;
    const bool de = qpath || (qc < 64);
    #pragma unroll
    for (int m = 0; m < 4; ++m) {
      const int pr0 = wr * 64 + m * 16 + lkb * 4;
      bf16x4 o;
      #pragma unroll
      for (int j = 0; j < 4; ++j) {
        float v = acc[m][n][j];
        if (de) v = v > 0.f ? v + 1.f : __expf(v);
        o[j] = (bf16_t)v;
      }
      const int u = pr0 >> 3;
      *(bf16x4*)((char*)ep + qc * 256 + ((u ^ (qc & 15)) << 4) + (pr0 & 7) * 2) = o;
    }
  }
  __syncthreads();
  if (qpath) {
    // coalesced q_phi store: row=token, 16B per lane-unit
    #pragma unroll
    for (int i = 0; i < 8; ++i) {
      const int flat = i * 256 + t;
      const int qc2 = flat >> 4, u2 = flat & 15;
      bf16x8 vv = *(const bf16x8*)((char*)ep + qc2 * 256 + ((u2 ^ (qc2 & 15)) << 4));
      *(bf16x8*)&q_phi[(tok0 + qc2) * 512 + cb * 128 + u2 * 8] = vv;
    }
  } else {
    // ---- second MFMA stage: partial kv[64kf][64vf] over this tile's 128 tokens ----
    // A = kφ rows 0-63 of ep, B = v rows 64-127; K = 128 tokens (4 K-steps).
    // Wave w owns vf quadrant [w*16, w*16+16); all waves read all kf rows.
    f32x4 acc2[4];
    #pragma unroll
    for (int m2 = 0; m2 < 4; ++m2) acc2[m2] = f32x4{0.f, 0.f, 0.f, 0.f};
    float ks2[4] = {0.f, 0.f, 0.f, 0.f};
    #pragma unroll
    for (int ks = 0; ks < 4; ++ks) {
      const int u = ks * 4 + lkb;  // token unit (8 toks)
      bf16x8 af2[4], bf2;
      #pragma unroll
      for (int m2 = 0; m2 < 4; ++m2) {
        const int fr = m2 * 16 + lrow;           // kf row
        af2[m2] = *(const bf16x8*)((char*)ep + fr * 256 + ((u ^ (fr & 15)) << 4));
      }
      {
        const int fr = 64 + w * 16 + lrow;       // vf row for this wave
        bf2 = *(const bf16x8*)((char*)ep + fr * 256 + ((u ^ (fr & 15)) << 4));
      }
      #pragma unroll
      for (int m2 = 0; m2 < 4; ++m2) {
        acc2[m2] = __builtin_amdgcn_mfma_f32_16x16x32_bf16(af2[m2], bf2, acc2[m2], 0, 0, 0);
        #pragma unroll
        for (int j = 0; j < 8; ++j) ks2[m2] += (float)af2[m2][j];
      }
    }
    const int bh = (int)(tok0 >> 12) * 8 + head;
    float* kvp = kv + (size_t)bh * 4096;
    #pragma unroll
    for (int m2 = 0; m2 < 4; ++m2)
      #pragma unroll
      for (int j = 0; j < 4; ++j)
        atomicAdd(&kvp[(m2 * 16 + lkb * 4 + j) * 64 + w * 16 + lrow], acc2[m2][j]);
    if (w == 0) {
      // lanes xor16/xor32 combine the 4 lkb token-subsets per kf row
      #pragma unroll
      for (int m2 = 0; m2 < 4; ++m2) {
        float s = ks2[m2];
        s += __shfl_xor(s, 16);
        s += __shfl_xor(s, 32);
        if (l < 16) atomicAdd(&ksum[(size_t)bh * 64 + m2 * 16 + l], s);
      }
    }
  }
}

// ---------------- W2T[b][j][h*64+f] = sum_d kv[b,h,f,d] * w_proj[h*64+d][j] ----------------
__global__ __launch_bounds__(256) void w2_kernel(const float* __restrict__ kv,
                                                 const float* __restrict__ w_proj,
                                                 bf16_t* __restrict__ W2T) {
  const int bh = blockIdx.x, b = bh >> 3, h = bh & 7;
  const int j0 = blockIdx.y * 64;
  const int t = threadIdx.x;
  __shared__ float kvs[64][64];
  __shared__ float wps[64][64];
  const float* kvp = kv + (size_t)bh * 4096;
  #pragma unroll
  for (int i = 0; i < 16; ++i) ((float*)kvs)[t + 256 * i] = kvp[t + 256 * i];
  {
    const int d = t >> 2, c16 = (t & 3) * 16;
    const float* src = w_proj + (size_t)(h * 64 + d) * 512 + j0 + c16;
    #pragma unroll
    for (int j = 0; j < 16; ++j) wps[d][c16 + j] = src[j];
  }
  __syncthreads();
  const int fq = t >> 4, jq = t & 15;
  float acc[4][4] = {};
  for (int d = 0; d < 64; ++d) {
    float kf[4], wj[4];
    #pragma unroll
    for (int i = 0; i < 4; ++i) kf[i] = kvs[fq * 4 + i][d];
    #pragma unroll
    for (int i = 0; i < 4; ++i) wj[i] = wps[d][jq * 4 + i];
    #pragma unroll
    for (int i = 0; i < 4; ++i)
      #pragma unroll
      for (int j = 0; j < 4; ++j) acc[i][j] += kf[i] * wj[j];
  }
  #pragma unroll
  for (int j = 0; j < 4; ++j)
    #pragma unroll
    for (int i = 0; i < 4; ++i)
      W2T[((size_t)b * 512 + j0 + jq * 4 + j) * 512 + h * 64 + fq * 4 + i] = (bf16_t)acc[i][j];
}

// ==================== output GEMM: fused z-scale (zq) in B-staging ====================
__global__ __launch_bounds__(256) void gemm_out(const bf16_t* __restrict__ W2T,
                                                const bf16_t* __restrict__ q_phi,
                                                const float* __restrict__ ksum,
                                                float* __restrict__ Cout,
                                                const float* __restrict__ bias) {
  __shared__ alignas(16) char smem[67584];  // A [0,32K) x2; B [32K,64K) x2; ksum [64K,66K)
  const int t = threadIdx.x, w = t >> 6, l = t & 63;
  const int hw = blockIdx.x;
  const int bid = (hw & 7) * 128 + (hw >> 3);   // 1024/8=128
  const int z = bid >> 7;
  const int rem = bid & 127;
  const int qblk = rem >> 2, pblk = rem & 3;
  const size_t tok0 = (size_t)qblk * 128;
  const int pj0 = pblk * 128;
  const bf16_t* Pp = W2T + ((size_t)z * 512 + pj0) * 512;

  const int wr = w >> 1, wc = w & 1;
  const int lrow = l & 15, lkb = l >> 4;
  const int st_r = l >> 3;
  const int st_c = ((l & 7) ^ st_r) * 8;
  const int token = t >> 1, half = t & 1;
  float* ks_lds = (float*)(smem + 65536);

  bf16x8 breg[4];
  auto loadB = [&](int c) {
    const bf16_t* p = q_phi + ((size_t)z * 4096 + tok0 + token) * 512 + c * 64 + half * 32;
    breg[0] = *(const bf16x8*)p;
    breg[1] = *(const bf16x8*)(p + 8);
    breg[2] = *(const bf16x8*)(p + 16);
    breg[3] = *(const bf16x8*)(p + 24);
  };
  auto stageA = [&](int s) {
    #pragma unroll
    for (int c = 0; c < 4; ++c) {
      const int q8 = c * 4 + w;
      gload16(Pp + (size_t)(q8 * 8 + st_r) * 512 + s * 64 + st_c,
              smem + (s & 1) * 16384 + q8 * 1024);
    }
  };
  auto procB = [&](int c) {
    const f32x4* ksv = (const f32x4*)(ks_lds + c * 64 + half * 32);
    float vals[32];
    float dot = 0.f;
    #pragma unroll
    for (int g = 0; g < 8; ++g) {
      const f32x4 kk = ksv[g];
      #pragma unroll
      for (int j = 0; j < 4; ++j) {
        const float v = (float)breg[g >> 1][(g & 1) * 4 + j];
        vals[g * 4 + j] = v;
        dot += v * kk[j];
      }
    }
    dot += __shfl_xor(dot, 1);  // lanes 2i,2i+1 share a token
    const float zz = 1.f / dot;
    char* dst = smem + 32768 + (c & 1) * 16384;
    #pragma unroll
    for (int g = 0; g < 4; ++g) {
      bf16x8 o;
      #pragma unroll
      for (int j = 0; j < 8; ++j) o[j] = (bf16_t)(vals[g * 8 + j] * zz);
      const int uk = half * 4 + g;
      *(bf16x8*)(dst + token * 128 + ((uk ^ (token & 7)) << 4)) = o;
    }
  };

  // prologue: ksum -> LDS; then chunk 0 staged
  {
    const f32x2 kk = *(const f32x2*)&ksum[(size_t)z * 512 + t * 2];
    *(f32x2*)&ks_lds[t * 2] = kk;
  }
  __syncthreads();
  loadB(0);
  stageA(0);
  procB(0);
  VMW(0);
  __syncthreads();

  f32x4 acc[4][4];
  #pragma unroll
  for (int m = 0; m < 4; ++m)
    #pragma unroll
    for (int n = 0; n < 4; ++n) acc[m][n] = f32x4{0.f, 0.f, 0.f, 0.f};

  for (int kt = 0; kt < 8; ++kt) {
    const char* PsB = smem + (kt & 1) * 16384;
    const char* QsB = smem + 32768 + (kt & 1) * 16384;
    bf16x8 pf[4][2], qf[4][2];
    #pragma unroll
    for (int m = 0; m < 4; ++m) {
      const int r = wr * 64 + m * 16 + lrow;
      #pragma unroll
      for (int kk = 0; kk < 2; ++kk) {
        const int kb = lkb + kk * 4;
        pf[m][kk] = *(const bf16x8*)(PsB + r * 128 + (((kb ^ (r & 7)) & 7) << 4));
      }
    }
    #pragma unroll
    for (int n = 0; n < 4; ++n) {
      const int r = wc * 64 + n * 16 + lrow;
      #pragma unroll
      for (int kk = 0; kk < 2; ++kk) {
        const int kb = lkb + kk * 4;
        qf[n][kk] = *(const bf16x8*)(QsB + r * 128 + (((kb ^ (r & 7)) & 7) << 4));
      }
    }
    if (kt + 1 < 8) { loadB(kt + 1); stageA(kt + 1); }
    #pragma unroll
    for (int m = 0; m < 4; ++m)
      #pragma unroll
      for (int n = 0; n < 4; ++n) {
        acc[m][n] = __builtin_amdgcn_mfma_f32_16x16x32_bf16(pf[m][0], qf[n][0], acc[m][n], 0, 0, 0);
        acc[m][n] = __builtin_amdgcn_mfma_f32_16x16x32_bf16(pf[m][1], qf[n][1], acc[m][n], 0, 0, 0);
      }
    if (kt + 1 < 8) { procB(kt + 1); VMW(0); }
    __syncthreads();
  }

  // epilogue: two phases of [64 token-rows][128 j] f32 (32 KB each) in smem[0,32K)
  float* ep = (float*)smem;
  #pragma unroll
  for (int p = 0; p < 2; ++p) {
    if (p) __syncthreads();
    #pragma unroll
    for (int nn2 = 0; nn2 < 2; ++nn2) {
      const int n = p * 2 + nn2;
      const int r6 = wc * 32 + (n & 1) * 16 + lrow;
      #pragma unroll
      for (int m = 0; m < 4; ++m) {
        const int pr0 = wr * 64 + m * 16 + lkb * 4;
        f32x4 v = acc[m][n];
        const f32x4 bv = *(const f32x4*)&bias[pj0 + pr0];
        #pragma unroll
        for (int j = 0; j < 4; ++j) v[j] += bv[j];
        const int u = pr0 >> 2;
        *(f32x4*)((char*)ep + r6 * 512 + ((u ^ (r6 & 31)) << 4)) = v;
      }
    }
    __syncthreads();
    #pragma unroll
    for (int i = 0; i < 8; ++i) {
      const int flat = i * 256 + t;
      const int r6 = flat >> 5, u2 = flat & 31;
      f32x4 v = *(const f32x4*)((char*)ep + r6 * 512 + ((u2 ^ (r6 & 31)) << 4));
      const int qc = (r6 >> 5) * 64 + p * 32 + (r6 & 31);
      *(f32x4*)&Cout[((size_t)z * 4096 + tok0 + qc) * 512 + pj0 + u2 * 4] = v;
    }
  }
}

extern "C" void kernel_launch(void* const* d_in, const int* in_sizes, int n_in,
                              void* d_out, int out_size, void* d_ws, size_t ws_size,
                              hipStream_t stream) {
  const float* x      = (const float*)d_in[0];
  const float* w_qkv  = (const float*)d_in[1];
  const float* proj   = (const float*)d_in[2];
  const float* w_proj = (const float*)d_in[3];
  const float* b_proj = (const float*)d_in[4];
  float* out = (float*)d_out;
  char* ws = (char*)d_ws;

  // workspace layout (bytes)
  bf16_t* WeffT = (bf16_t*)(ws + 0);           // 1536*512*2   =  1,572,864
  bf16_t* q_phi = (bf16_t*)(ws + 1572864);     // 32768*512*2  = 33,554,432
  float*  kv    = (float*)(ws + 35127296);     // 64*64*64*4   =  1,048,576
  float*  ksum  = (float*)(ws + 36175872);     // 64*64*4      =     16,384
  bf16_t* W2T   = (bf16_t*)(ws + 36192256);    // 8*512*512*2  =  4,194,304
                                               // total ~40.4 MB

  prep_qk<<<dim3(16, 8), 256, 0, stream>>>(w_qkv, proj, WeffT);
  prep_v<<<dim3(16, 16), 256, 0, stream>>>(w_qkv, WeffT);
  hipMemsetAsync(kv, 0, 1048576 + 16384, stream);
  gemm_qkv<<<3072, 256, 0, stream>>>(x, WeffT, q_phi, kv, ksum);
  w2_kernel<<<dim3(64, 8), 256, 0, stream>>>(kv, w_proj, W2T);
  gemm_out<<<1024, 256, 0, stream>>>(W2T, q_phi, ksum, out, b_proj);
}

// Round 17
// 164.692 us; speedup vs baseline: 2.1030x; 1.0104x over previous
//
#include <hip/hip_runtime.h>
#include <hip/hip_bf16.h>

typedef __bf16 bf16_t;
typedef __bf16 bf16x4 __attribute__((ext_vector_type(4)));
typedef __bf16 bf16x8 __attribute__((ext_vector_type(8)));
typedef float f32x2 __attribute__((ext_vector_type(2)));
typedef float f32x4 __attribute__((ext_vector_type(4)));

__device__ __forceinline__ void gload16(const void* g, void* l) {
  __builtin_amdgcn_global_load_lds((const __attribute__((address_space(1))) void*)g,
                                   (__attribute__((address_space(3))) void*)l, 16, 0, 0);
}

#define VMW(n) asm volatile("s_waitcnt vmcnt(" #n ")" ::: "memory")

// ---------------- prep: fold proj into w_qkv (q,k halves) ----------------
__global__ __launch_bounds__(256) void prep_qk(const float* __restrict__ w_qkv,
                                               const float* __restrict__ proj,
                                               bf16_t* __restrict__ WeffT) {
  const int half = blockIdx.x >> 3, h = blockIdx.x & 7;
  const int i0 = blockIdx.y * 64;
  __shared__ float P[64 * 64];   // [d][f] == proj[h] layout
  __shared__ float Wt[64][65];   // [ii][d], padded
  const int t = threadIdx.x;
  #pragma unroll
  for (int r = 0; r < 16; ++r) P[t + 256 * r] = proj[(size_t)h * 4096 + t + 256 * r];
  #pragma unroll
  for (int r = 0; r < 16; ++r) {
    const int idx = t + 256 * r;
    Wt[idx >> 6][idx & 63] =
        w_qkv[(size_t)(i0 + (idx >> 6)) * 1536 + half * 512 + h * 64 + (idx & 63)];
  }
  __syncthreads();
  const int i = t & 63, fg = t >> 6;
  for (int f = fg; f < 64; f += 4) {
    float s = 0.f;
    #pragma unroll
    for (int d = 0; d < 64; ++d) s += Wt[i][d] * P[d * 64 + f];
    WeffT[(size_t)(half * 512 + h * 64 + f) * 512 + i0 + i] = (bf16_t)s;
  }
}

// ---------------- prep: v passthrough transpose ----------------
__global__ __launch_bounds__(256) void prep_v(const float* __restrict__ w_qkv,
                                              bf16_t* __restrict__ WeffT) {
  __shared__ bf16_t tile[32][33];
  const int i0 = blockIdx.x * 32, n0 = blockIdx.y * 32;
  const int tn = threadIdx.x & 31, ti = threadIdx.x >> 5;
  #pragma unroll
  for (int p = 0; p < 4; ++p) {
    const int i = ti + p * 8;
    tile[i][tn] = (bf16_t)w_qkv[(size_t)(i0 + i) * 1536 + 1024 + n0 + tn];
  }
  __syncthreads();
  #pragma unroll
  for (int p = 0; p < 4; ++p) {
    const int n = ti + p * 8;
    WeffT[(size_t)(1024 + n0 + n) * 512 + i0 + tn] = tile[tn][n];
  }
}

// ==================== merged QKV GEMM v9: H tile repacked to 128B rows ====================
// R16 structure (3072 blocks x 256 thr, XCD-chunked, fenced __syncthreads per K-step,
// BK=32, 16 K-steps, fused cast + fused kv-reduction) with ONE change: the H tile is
// repacked so LDS row j (0..63, 128B = 8x16B units) holds WeffT rows j AND j+64.
// Physical unit u of row j stores logical lg = u ^ (j&7): half = lg>>2 (0 -> Wp0 row j,
// 1 -> Wp1 row j), kslot = lg&3. Read for WeffT row r, k-slot lkb:
//   u = ((r>>6)*4 + lkb) ^ (r&7), byte = (r&63)*128 + u*16.   (4+lkb == 4^lkb)
// Per wave-read this gives 8 lanes/unit (R10's low-conflict pattern) instead of the
// old 64B-row tile's 16 lanes/unit (16-way conflict, 7.08M counter). F unchanged.
__global__ __launch_bounds__(256) void gemm_qkv(const float* __restrict__ x,
                                                const bf16_t* __restrict__ WeffT,
                                                bf16_t* __restrict__ q_phi,
                                                float* __restrict__ kv,
                                                float* __restrict__ ksum) {
  __shared__ alignas(16) char smem[49152];  // F [0,32K) x2; H [32K,48K) x2
  const int t = threadIdx.x, w = t >> 6, l = t & 63;
  const int hw = blockIdx.x;
  const int bid = (hw & 7) * 384 + (hw >> 3);   // XCD-chunked (3072/8=384)
  const int tok_blk = bid / 12, cb = bid % 12;
  const size_t tok0 = (size_t)tok_blk * 128;
  const bool qpath = (cb < 4);
  const int head = cb - 4;                      // valid for kv blocks
  const float* Xp = x + tok0 * 512;
  const bf16_t* Wp0;
  const bf16_t* Wp1;
  if (qpath) {
    Wp0 = WeffT + (size_t)cb * 128 * 512;            // q rows 0-63 of this 128-chunk
    Wp1 = Wp0 + (size_t)64 * 512;                    // q rows 64-127
  } else {
    Wp0 = WeffT + (size_t)(512 + head * 64) * 512;   // kφ-head h
    Wp1 = WeffT + (size_t)(1024 + head * 64) * 512;  // v-head h
  }

  const int wr = w >> 1, wc = w & 1;
  const int lrow = l & 15, lkb = l >> 4;

  // staging geometry (pre-swizzled global source, linear LDS dest)
  const int sr8 = t >> 3, su8 = t & 7;  // F tile: row c*32+sr8, 16B unit su8
  const size_t fcol = (size_t)((su8 ^ (sr8 & 7)) * 4);        // f32 units of 4

  // H staging: thread t -> LDS row j = c*32 + (t>>3), phys unit u = t&7, dest = c*4096+t*16.
  // logical lg = u ^ (j&7) -> half = lg>>2, kslot = lg&3.
  const int h_j = t >> 3;
  const int h_lg = (t & 7) ^ ((t >> 3) & 7);
  const int h_half = h_lg >> 2, h_ks = h_lg & 3;

  auto stageF = [&](int s) {
    char* dst = smem + (s & 1) * 16384;
    #pragma unroll
    for (int c = 0; c < 4; ++c)
      gload16(Xp + (size_t)(c * 32 + sr8) * 512 + s * 32 + fcol, dst + c * 4096 + t * 16);
  };
  auto stageH = [&](int s) {
    char* dst = smem + 32768 + (s & 1) * 8192;
    #pragma unroll
    for (int c = 0; c < 2; ++c) {
      const int j = c * 32 + h_j;
      const bf16_t* src = (h_half ? Wp1 : Wp0) + (size_t)j * 512 + s * 32 + h_ks * 8;
      gload16(src, dst + c * 4096 + t * 16);
    }
  };

  f32x4 acc[4][4];
  #pragma unroll
  for (int m = 0; m < 4; ++m)
    #pragma unroll
    for (int n = 0; n < 4; ++n) acc[m][n] = f32x4{0.f, 0.f, 0.f, 0.f};

  // prologue: tile 0 into buf 0; barrier drains (implicit vmcnt(0))
  stageF(0); stageH(0);
  __syncthreads();

  for (int kt = 0; kt < 16; ++kt) {
    if (kt + 1 < 16) { stageF(kt + 1); stageH(kt + 1); }  // prefetch into other buf
    const char* Fs = smem + (kt & 1) * 16384;
    const char* Hs = smem + 32768 + (kt & 1) * 8192;
    bf16x8 pf[4], qf[4];
    if (qpath) {
      #pragma unroll
      for (int m = 0; m < 4; ++m) {
        const int r = wr * 64 + m * 16 + lrow;  // WeffT rows 0-127
        const int u = (((r >> 6) << 2) + lkb) ^ (r & 7);
        pf[m] = *(const bf16x8*)(Hs + (r & 63) * 128 + (u << 4));
      }
      #pragma unroll
      for (int n = 0; n < 4; ++n) {
        const int r = wc * 64 + n * 16 + lrow;  // token rows
        const f32x4 a = *(const f32x4*)(Fs + r * 128 + (((2 * lkb) ^ (r & 7)) << 4));
        const f32x4 b = *(const f32x4*)(Fs + r * 128 + (((2 * lkb + 1) ^ (r & 7)) << 4));
        #pragma unroll
        for (int j = 0; j < 4; ++j) { qf[n][j] = (bf16_t)a[j]; qf[n][4 + j] = (bf16_t)b[j]; }
      }
    } else {
      #pragma unroll
      for (int m = 0; m < 4; ++m) {
        const int r = wr * 64 + m * 16 + lrow;  // token rows
        const f32x4 a = *(const f32x4*)(Fs + r * 128 + (((2 * lkb) ^ (r & 7)) << 4));
        const f32x4 b = *(const f32x4*)(Fs + r * 128 + (((2 * lkb + 1) ^ (r & 7)) << 4));
        #pragma unroll
        for (int j = 0; j < 4; ++j) { pf[m][j] = (bf16_t)a[j]; pf[m][4 + j] = (bf16_t)b[j]; }
      }
      #pragma unroll
      for (int n = 0; n < 4; ++n) {
        const int r = wc * 64 + n * 16 + lrow;  // WeffT rows 0-127
        const int u = (((r >> 6) << 2) + lkb) ^ (r & 7);
        qf[n] = *(const bf16x8*)(Hs + (r & 63) * 128 + (u << 4));
      }
    }
    #pragma unroll
    for (int m = 0; m < 4; ++m)
      #pragma unroll
      for (int n = 0; n < 4; ++n)
        acc[m][n] = __builtin_amdgcn_mfma_f32_16x16x32_bf16(pf[m], qf[n], acc[m][n], 0, 0, 0);
    __syncthreads();  // readers done with cur; prefetch landed (drain)
  }

  // ---- epilogue write: ep tile [128 qrows][128 prows] bf16, 16B-unit XOR swizzle ----
  bf16_t* ep = (bf16_t*)smem;  // 32 KB, rows 256 B
  #pragma unroll
  for (int n = 0; n < 4; ++n) {
    const int qc = wc * 64 + n * 16 + lrow;
    const bool de = qpath || (qc < 64);
    #pragma unroll
    for (int m = 0; m < 4; ++m) {
      const int pr0 = wr * 64 + m * 16 + lkb * 4;
      bf16x4 o;
      #pragma unroll
      for (int j = 0; j < 4; ++j) {
        float v = acc[m][n][j];
        if (de) v = v > 0.f ? v + 1.f : __expf(v);
        o[j] = (bf16_t)v;
      }
      const int u = pr0 >> 3;
      *(bf16x4*)((char*)ep + qc * 256 + ((u ^ (qc & 15)) << 4) + (pr0 & 7) * 2) = o;
    }
  }
  __syncthreads();
  if (qpath) {
    // coalesced q_phi store: row=token, 16B per lane-unit
    #pragma unroll
    for (int i = 0; i < 8; ++i) {
      const int flat = i * 256 + t;
      const int qc2 = flat >> 4, u2 = flat & 15;
      bf16x8 vv = *(const bf16x8*)((char*)ep + qc2 * 256 + ((u2 ^ (qc2 & 15)) << 4));
      *(bf16x8*)&q_phi[(tok0 + qc2) * 512 + cb * 128 + u2 * 8] = vv;
    }
  } else {
    // ---- second MFMA stage: partial kv[64kf][64vf] over this tile's 128 tokens ----
    f32x4 acc2[4];
    #pragma unroll
    for (int m2 = 0; m2 < 4; ++m2) acc2[m2] = f32x4{0.f, 0.f, 0.f, 0.f};
    float ks2[4] = {0.f, 0.f, 0.f, 0.f};
    #pragma unroll
    for (int ks = 0; ks < 4; ++ks) {
      const int u = ks * 4 + lkb;  // token unit (8 toks)
      bf16x8 af2[4], bf2;
      #pragma unroll
      for (int m2 = 0; m2 < 4; ++m2) {
        const int fr = m2 * 16 + lrow;           // kf row
        af2[m2] = *(const bf16x8*)((char*)ep + fr * 256 + ((u ^ (fr & 15)) << 4));
      }
      {
        const int fr = 64 + w * 16 + lrow;       // vf row for this wave
        bf2 = *(const bf16x8*)((char*)ep + fr * 256 + ((u ^ (fr & 15)) << 4));
      }
      #pragma unroll
      for (int m2 = 0; m2 < 4; ++m2) {
        acc2[m2] = __builtin_amdgcn_mfma_f32_16x16x32_bf16(af2[m2], bf2, acc2[m2], 0, 0, 0);
        #pragma unroll
        for (int j = 0; j < 8; ++j) ks2[m2] += (float)af2[m2][j];
      }
    }
    const int bh = (int)(tok0 >> 12) * 8 + head;
    float* kvp = kv + (size_t)bh * 4096;
    #pragma unroll
    for (int m2 = 0; m2 < 4; ++m2)
      #pragma unroll
      for (int j = 0; j < 4; ++j)
        atomicAdd(&kvp[(m2 * 16 + lkb * 4 + j) * 64 + w * 16 + lrow], acc2[m2][j]);
    if (w == 0) {
      #pragma unroll
      for (int m2 = 0; m2 < 4; ++m2) {
        float s = ks2[m2];
        s += __shfl_xor(s, 16);
        s += __shfl_xor(s, 32);
        if (l < 16) atomicAdd(&ksum[(size_t)bh * 64 + m2 * 16 + l], s);
      }
    }
  }
}

// ---------------- W2T[b][j][h*64+f] = sum_d kv[b,h,f,d] * w_proj[h*64+d][j] ----------------
__global__ __launch_bounds__(256) void w2_kernel(const float* __restrict__ kv,
                                                 const float* __restrict__ w_proj,
                                                 bf16_t* __restrict__ W2T) {
  const int bh = blockIdx.x, b = bh >> 3, h = bh & 7;
  const int j0 = blockIdx.y * 64;
  const int t = threadIdx.x;
  __shared__ float kvs[64][64];
  __shared__ float wps[64][64];
  const float* kvp = kv + (size_t)bh * 4096;
  #pragma unroll
  for (int i = 0; i < 16; ++i) ((float*)kvs)[t + 256 * i] = kvp[t + 256 * i];
  {
    const int d = t >> 2, c16 = (t & 3) * 16;
    const float* src = w_proj + (size_t)(h * 64 + d) * 512 + j0 + c16;
    #pragma unroll
    for (int j = 0; j < 16; ++j) wps[d][c16 + j] = src[j];
  }
  __syncthreads();
  const int fq = t >> 4, jq = t & 15;
  float acc[4][4] = {};
  for (int d = 0; d < 64; ++d) {
    float kf[4], wj[4];
    #pragma unroll
    for (int i = 0; i < 4; ++i) kf[i] = kvs[fq * 4 + i][d];
    #pragma unroll
    for (int i = 0; i < 4; ++i) wj[i] = wps[d][jq * 4 + i];
    #pragma unroll
    for (int i = 0; i < 4; ++i)
      #pragma unroll
      for (int j = 0; j < 4; ++j) acc[i][j] += kf[i] * wj[j];
  }
  #pragma unroll
  for (int j = 0; j < 4; ++j)
    #pragma unroll
    for (int i = 0; i < 4; ++i)
      W2T[((size_t)b * 512 + j0 + jq * 4 + j) * 512 + h * 64 + fq * 4 + i] = (bf16_t)acc[i][j];
}

// ==================== output GEMM: fused z-scale (zq) in B-staging ====================
__global__ __launch_bounds__(256) void gemm_out(const bf16_t* __restrict__ W2T,
                                                const bf16_t* __restrict__ q_phi,
                                                const float* __restrict__ ksum,
                                                float* __restrict__ Cout,
                                                const float* __restrict__ bias) {
  __shared__ alignas(16) char smem[67584];  // A [0,32K) x2; B [32K,64K) x2; ksum [64K,66K)
  const int t = threadIdx.x, w = t >> 6, l = t & 63;
  const int hw = blockIdx.x;
  const int bid = (hw & 7) * 128 + (hw >> 3);   // 1024/8=128
  const int z = bid >> 7;
  const int rem = bid & 127;
  const int qblk = rem >> 2, pblk = rem & 3;
  const size_t tok0 = (size_t)qblk * 128;
  const int pj0 = pblk * 128;
  const bf16_t* Pp = W2T + ((size_t)z * 512 + pj0) * 512;

  const int wr = w >> 1, wc = w & 1;
  const int lrow = l & 15, lkb = l >> 4;
  const int st_r = l >> 3;
  const int st_c = ((l & 7) ^ st_r) * 8;
  const int token = t >> 1, half = t & 1;
  float* ks_lds = (float*)(smem + 65536);

  bf16x8 breg[4];
  auto loadB = [&](int c) {
    const bf16_t* p = q_phi + ((size_t)z * 4096 + tok0 + token) * 512 + c * 64 + half * 32;
    breg[0] = *(const bf16x8*)p;
    breg[1] = *(const bf16x8*)(p + 8);
    breg[2] = *(const bf16x8*)(p + 16);
    breg[3] = *(const bf16x8*)(p + 24);
  };
  auto stageA = [&](int s) {
    #pragma unroll
    for (int c = 0; c < 4; ++c) {
      const int q8 = c * 4 + w;
      gload16(Pp + (size_t)(q8 * 8 + st_r) * 512 + s * 64 + st_c,
              smem + (s & 1) * 16384 + q8 * 1024);
    }
  };
  auto procB = [&](int c) {
    const f32x4* ksv = (const f32x4*)(ks_lds + c * 64 + half * 32);
    float vals[32];
    float dot = 0.f;
    #pragma unroll
    for (int g = 0; g < 8; ++g) {
      const f32x4 kk = ksv[g];
      #pragma unroll
      for (int j = 0; j < 4; ++j) {
        const float v = (float)breg[g >> 1][(g & 1) * 4 + j];
        vals[g * 4 + j] = v;
        dot += v * kk[j];
      }
    }
    dot += __shfl_xor(dot, 1);  // lanes 2i,2i+1 share a token
    const float zz = 1.f / dot;
    char* dst = smem + 32768 + (c & 1) * 16384;
    #pragma unroll
    for (int g = 0; g < 4; ++g) {
      bf16x8 o;
      #pragma unroll
      for (int j = 0; j < 8; ++j) o[j] = (bf16_t)(vals[g * 8 + j] * zz);
      const int uk = half * 4 + g;
      *(bf16x8*)(dst + token * 128 + ((uk ^ (token & 7)) << 4)) = o;
    }
  };

  // prologue: ksum -> LDS; then chunk 0 staged
  {
    const f32x2 kk = *(const f32x2*)&ksum[(size_t)z * 512 + t * 2];
    *(f32x2*)&ks_lds[t * 2] = kk;
  }
  __syncthreads();
  loadB(0);
  stageA(0);
  procB(0);
  VMW(0);
  __syncthreads();

  f32x4 acc[4][4];
  #pragma unroll
  for (int m = 0; m < 4; ++m)
    #pragma unroll
    for (int n = 0; n < 4; ++n) acc[m][n] = f32x4{0.f, 0.f, 0.f, 0.f};

  for (int kt = 0; kt < 8; ++kt) {
    const char* PsB = smem + (kt & 1) * 16384;
    const char* QsB = smem + 32768 + (kt & 1) * 16384;
    bf16x8 pf[4][2], qf[4][2];
    #pragma unroll
    for (int m = 0; m < 4; ++m) {
      const int r = wr * 64 + m * 16 + lrow;
      #pragma unroll
      for (int kk = 0; kk < 2; ++kk) {
        const int kb = lkb + kk * 4;
        pf[m][kk] = *(const bf16x8*)(PsB + r * 128 + (((kb ^ (r & 7)) & 7) << 4));
      }
    }
    #pragma unroll
    for (int n = 0; n < 4; ++n) {
      const int r = wc * 64 + n * 16 + lrow;
      #pragma unroll
      for (int kk = 0; kk < 2; ++kk) {
        const int kb = lkb + kk * 4;
        qf[n][kk] = *(const bf16x8*)(QsB + r * 128 + (((kb ^ (r & 7)) & 7) << 4));
      }
    }
    if (kt + 1 < 8) { loadB(kt + 1); stageA(kt + 1); }
    #pragma unroll
    for (int m = 0; m < 4; ++m)
      #pragma unroll
      for (int n = 0; n < 4; ++n) {
        acc[m][n] = __builtin_amdgcn_mfma_f32_16x16x32_bf16(pf[m][0], qf[n][0], acc[m][n], 0, 0, 0);
        acc[m][n] = __builtin_amdgcn_mfma_f32_16x16x32_bf16(pf[m][1], qf[n][1], acc[m][n], 0, 0, 0);
      }
    if (kt + 1 < 8) { procB(kt + 1); VMW(0); }
    __syncthreads();
  }

  // epilogue: two phases of [64 token-rows][128 j] f32 (32 KB each) in smem[0,32K)
  float* ep = (float*)smem;
  #pragma unroll
  for (int p = 0; p < 2; ++p) {
    if (p) __syncthreads();
    #pragma unroll
    for (int nn2 = 0; nn2 < 2; ++nn2) {
      const int n = p * 2 + nn2;
      const int r6 = wc * 32 + (n & 1) * 16 + lrow;
      #pragma unroll
      for (int m = 0; m < 4; ++m) {
        const int pr0 = wr * 64 + m * 16 + lkb * 4;
        f32x4 v = acc[m][n];
        const f32x4 bv = *(const f32x4*)&bias[pj0 + pr0];
        #pragma unroll
        for (int j = 0; j < 4; ++j) v[j] += bv[j];
        const int u = pr0 >> 2;
        *(f32x4*)((char*)ep + r6 * 512 + ((u ^ (r6 & 31)) << 4)) = v;
      }
    }
    __syncthreads();
    #pragma unroll
    for (int i = 0; i < 8; ++i) {
      const int flat = i * 256 + t;
      const int r6 = flat >> 5, u2 = flat & 31;
      f32x4 v = *(const f32x4*)((char*)ep + r6 * 512 + ((u2 ^ (r6 & 31)) << 4));
      const int qc = (r6 >> 5) * 64 + p * 32 + (r6 & 31);
      *(f32x4*)&Cout[((size_t)z * 4096 + tok0 + qc) * 512 + pj0 + u2 * 4] = v;
    }
  }
}

extern "C" void kernel_launch(void* const* d_in, const int* in_sizes, int n_in,
                              void* d_out, int out_size, void* d_ws, size_t ws_size,
                              hipStream_t stream) {
  const float* x      = (const float*)d_in[0];
  const float* w_qkv  = (const float*)d_in[1];
  const float* proj   = (const float*)d_in[2];
  const float* w_proj = (const float*)d_in[3];
  const float* b_proj = (const float*)d_in[4];
  float* out = (float*)d_out;
  char* ws = (char*)d_ws;

  // workspace layout (bytes)
  bf16_t* WeffT = (bf16_t*)(ws + 0);           // 1536*512*2   =  1,572,864
  bf16_t* q_phi = (bf16_t*)(ws + 1572864);     // 32768*512*2  = 33,554,432
  float*  kv    = (float*)(ws + 35127296);     // 64*64*64*4   =  1,048,576
  float*  ksum  = (float*)(ws + 36175872);     // 64*64*4      =     16,384
  bf16_t* W2T   = (bf16_t*)(ws + 36192256);    // 8*512*512*2  =  4,194,304
                                               // total ~40.4 MB

  prep_qk<<<dim3(16, 8), 256, 0, stream>>>(w_qkv, proj, WeffT);
  prep_v<<<dim3(16, 16), 256, 0, stream>>>(w_qkv, WeffT);
  hipMemsetAsync(kv, 0, 1048576 + 16384, stream);
  gemm_qkv<<<3072, 256, 0, stream>>>(x, WeffT, q_phi, kv, ksum);
  w2_kernel<<<dim3(64, 8), 256, 0, stream>>>(kv, w_proj, W2T);
  gemm_out<<<1024, 256, 0, stream>>>(W2T, q_phi, ksum, out, b_proj);
}